// Round 21
// baseline (158.582 us; speedup 1.0000x reference)
//
#include <hip/hip_runtime.h>
#include <stdint.h>

typedef __attribute__((ext_vector_type(8))) short  bf16x8;
typedef __attribute__((ext_vector_type(4))) short  short4v;
typedef __attribute__((ext_vector_type(4))) float  f32x4;
typedef __attribute__((ext_vector_type(4))) float  float4v;

#define VMW(N) asm volatile("s_waitcnt vmcnt(" #N ")" ::: "memory")
#define LKW(N) asm volatile("s_waitcnt lgkmcnt(" #N ")" ::: "memory")
#define BAR()  asm volatile("s_barrier" ::: "memory")

__device__ __forceinline__ short f2bf(float f) {
  union { float f; uint32_t u; } c; c.f = f;
  uint32_t u = c.u;
  uint32_t r = (u + 0x7FFFu + ((u >> 16) & 1u)) >> 16;
  return (short)(uint16_t)r;
}

// hardware bf16 convert (compiler emits v_cvt_pk_bf16_f32 for pairs)
__device__ __forceinline__ short f2bf_hw(float f) {
  return __builtin_bit_cast(short, (__bf16)f);
}

__device__ __forceinline__ void gload_lds16(const void* g, void* l) {
  __builtin_amdgcn_global_load_lds(
      (const __attribute__((address_space(1))) void*)g,
      (__attribute__((address_space(3))) void*)l, 16, 0, 0);
}

// ---------- fused prep: x cast (blocks 0..1023), Wc^T (1024..1791), Wo^T ----------
__device__ __forceinline__ void transpose_body(
    const float* __restrict__ in, short* __restrict__ out, int R, int C,
    int bx, int by, short (*tile)[65]) {
  int bc = bx * 64, br = by * 64;
  int tc = threadIdx.x & 63, tr = threadIdx.x >> 6;  // tr 0..3
#pragma unroll
  for (int i = 0; i < 64; i += 4)
    tile[tc][tr + i] = f2bf(in[(size_t)(br + tr + i) * C + bc + tc]);
  __syncthreads();
#pragma unroll
  for (int i = 0; i < 64; i += 4)
    out[(size_t)(bc + tr + i) * R + br + tc] = tile[tr + i][tc];
}

__global__ __launch_bounds__(256) void k_prep(
    const float* __restrict__ x, short* __restrict__ xb, int n4,
    const float* __restrict__ Wc, short* __restrict__ wct,
    const float* __restrict__ Wo, short* __restrict__ wot) {
  __shared__ short tile[64][65];
  const int id = blockIdx.x;
  if (id < 1024) {  // cast: grid-stride, 1024 blocks
    const int stride = 1024 * 256;
    for (int i = id * 256 + threadIdx.x; i < n4; i += stride) {
      float4v v = *(const float4v*)(x + (size_t)i * 4);
      short4v o;
      o.x = f2bf(v.x); o.y = f2bf(v.y); o.z = f2bf(v.z); o.w = f2bf(v.w);
      *(short4v*)(xb + (size_t)i * 4) = o;
    }
  } else if (id < 1024 + 768) {  // Wc [1024][3072] -> wct [3072][1024]
    int t = id - 1024;
    transpose_body(Wc, wct, 1024, 3072, t % 48, t / 48, tile);
  } else {  // Wo [1024][1024] -> wot [1024][1024]
    int t = id - 1792;
    transpose_body(Wo, wot, 1024, 1024, t & 15, t >> 4, tile);
  }
}

// ---------- QKV GEMM: 256x256 8-phase (R8-verified math) + waves_per_eu(2,2) ----
// R7/R8 failure signature was VGPR=112 + 35MB scratch spill: launch_bounds'
// 2nd arg is only a MIN waves/EU, so the allocator still targeted high
// occupancy and spilled acc[8][4]. amdgpu_waves_per_eu(2,2) caps the MAX at
// 2 waves/EU (the true occupancy: 128 KB LDS = 1 block/CU), unlocking the
// 256-VGPR budget. Data mapping identical to the R7/R8 passing kernel.
template <bool F32OUT>
__global__ __launch_bounds__(512)
__attribute__((amdgpu_waves_per_eu(2, 2))) void k_g256(
    const short* __restrict__ A, const short* __restrict__ BT,
    const float* __restrict__ bias, void* __restrict__ Cout,
    int M, int N, int K, int nbn) {
  __shared__ short As[2][2][128][64];
  __shared__ short Bs[2][2][128][64];
  const int tid = threadIdx.x;
  const int w = tid >> 6, l = tid & 63;
  const int fr = l & 15, fg = l >> 4;
  const int wm = w >> 2, wn = w & 3;   // 2M x 4N wave grid

  // XCD-bijective swizzle (grid % 8 == 0: QKV grid = 384)
  const int q8 = gridDim.x >> 3;
  const int wg = (blockIdx.x & 7) * q8 + (blockIdx.x >> 3);
  const int bm = wg / nbn, bn = wg % nbn;
  const size_t brow = (size_t)bm << 8;
  const int bcol = bn << 8;
  const int NT = K >> 6;

  const int srow = tid >> 3;                    // 0..63
  const int soct = (tid & 7) ^ (srow & 7);
  const int sx = fr & 7;

  f32x4 acc[8][4] = {};

#define STAGE_A(bufv, halfv, kt)                                               \
  {                                                                            \
    _Pragma("unroll") for (int j = 0; j < 2; ++j) {                            \
      const short* g = A + (brow + (halfv)*128 + j * 64 + srow) * (size_t)K +  \
                       (kt)*64 + soct * 8;                                     \
      gload_lds16(g, (char*)&As[bufv][halfv][j * 64 + w * 8][0]);              \
    }                                                                          \
  }
#define STAGE_B(bufv, halfv, kt)                                               \
  {                                                                            \
    _Pragma("unroll") for (int j = 0; j < 2; ++j) {                            \
      const short* g = BT +                                                    \
                       ((size_t)(bcol + (halfv)*128 + j * 64 + srow)) * K +    \
                       (kt)*64 + soct * 8;                                     \
      gload_lds16(g, (char*)&Bs[bufv][halfv][j * 64 + w * 8][0]);              \
    }                                                                          \
  }

  // prologue: full tile 0
  STAGE_A(0, 0, 0); STAGE_B(0, 0, 0); STAGE_A(0, 1, 0); STAGE_B(0, 1, 0);
  VMW(0);
  BAR();

  const int bhalf = wn >> 1, brow2 = (wn & 1) * 64;

  for (int t = 0; t < NT; ++t) {
    const int buf = t & 1, nbuf = buf ^ 1;
    bf16x8 bfr[4][2];
#pragma unroll
    for (int p = 0; p < 4; ++p) {
      bf16x8 afr[2][2];
#pragma unroll
      for (int i = 0; i < 2; ++i)
#pragma unroll
        for (int kk = 0; kk < 2; ++kk)
          afr[i][kk] = *(const bf16x8*)
              &As[buf][wm][(2 * p + i) * 16 + fr][((kk * 4 + fg) ^ sx) * 8];
      if (p == 0) {
#pragma unroll
        for (int nf = 0; nf < 4; ++nf)
#pragma unroll
          for (int kk = 0; kk < 2; ++kk)
            bfr[nf][kk] = *(const bf16x8*)
                &Bs[buf][bhalf][brow2 + nf * 16 + fr][((kk * 4 + fg) ^ sx) * 8];
      }
      if (t + 1 < NT) {
        if (p == 0) { STAGE_A(nbuf, 0, t + 1); STAGE_B(nbuf, 0, t + 1); }
        else if (p == 1) { STAGE_A(nbuf, 1, t + 1); STAGE_B(nbuf, 1, t + 1); }
      }
      if (p == 0) { LKW(8); }
      BAR();
      __builtin_amdgcn_s_setprio(1);
#pragma unroll
      for (int i = 0; i < 2; ++i)
#pragma unroll
        for (int nf = 0; nf < 4; ++nf)
#pragma unroll
          for (int kk = 0; kk < 2; ++kk)
            acc[2 * p + i][nf] = __builtin_amdgcn_mfma_f32_16x16x32_bf16(
                afr[i][kk], bfr[nf][kk], acc[2 * p + i][nf], 0, 0, 0);
      __builtin_amdgcn_s_setprio(0);
      if (p == 3 && t + 1 < NT) { VMW(0); }
      BAR();
    }
  }
#undef STAGE_A
#undef STAGE_B

#pragma unroll
  for (int nf = 0; nf < 4; ++nf) {
    const int col = bcol + wn * 64 + nf * 16 + fr;
    const float bv = bias[col];
#pragma unroll
    for (int mf = 0; mf < 8; ++mf) {
      const size_t row = brow + (size_t)(wm * 128 + mf * 16 + fg * 4);
#pragma unroll
      for (int r = 0; r < 4; ++r) {
        const float v = acc[mf][nf][r] + bv;
        if (F32OUT)
          ((float*)Cout)[(row + r) * (size_t)N + col] = v;
        else
          ((short*)Cout)[(row + r) * (size_t)N + col] = f2bf(v);
      }
    }
  }
}

// ------------- out-proj GEMM (R6/R15-verified): 128x128, BK=64, two-phase ------
template <bool F32OUT>
__global__ __launch_bounds__(256) void k_gemm2(
    const short* __restrict__ A, const short* __restrict__ BT,
    const float* __restrict__ bias, void* __restrict__ Cout,
    int M, int N, int K, int nbn) {
  __shared__ short SM[2][2][2][128][32];  // [buf][mat(A=0,B=1)][kh][row][kcol]
  const int tid = threadIdx.x;
  const int w = tid >> 6, l = tid & 63;
  const int fr = l & 15, fg = l >> 4;
  const int wm = w >> 1, wn = w & 1;

  const int q8 = gridDim.x >> 3;
  const int wg = (blockIdx.x & 7) * q8 + (blockIdx.x >> 3);
  const int bm = wg / nbn, bn = wg % nbn;
  const size_t brow = (size_t)bm << 7;
  const int bcol = bn << 7;

  const int NT = K >> 6;

  const int srow = l >> 2;
  const int soct = (l & 3) ^ ((l >> 3) & 3);
  const short* aG = A + (brow + srow) * (size_t)K + soct * 8;
  const short* bG = BT + ((size_t)(bcol + srow)) * K + soct * 8;
  const int slot8 = ((fg ^ ((fr >> 1) & 3)) << 3);

  f32x4 acc[4][4] = {};

#pragma unroll
  for (int s = 0; s < 6; ++s) {
    const int t = s >> 2, tau = s & 3, buf = t & 1, mat = tau & 1, kh = tau >> 1;
    const int kbase = t * 64 + kh * 32;
    const short* g0 = (mat ? bG : aG) + kbase;
#pragma unroll
    for (int j = 0; j < 2; ++j) {
      const int r0 = (w * 2 + j) * 16;
      gload_lds16(g0 + (size_t)r0 * K, (char*)&SM[buf][mat][kh][r0][0]);
    }
  }
  VMW(8);
  BAR();

  int sidx = 6;
  for (int t = 0; t < NT; ++t) {
    const int buf = t & 1;
#pragma unroll
    for (int p = 0; p < 2; ++p) {
      const int kh = p;
#pragma unroll
      for (int s = 0; s < 2; ++s) {
        if (sidx < NT * 4) {
          const int ts = sidx >> 2, tau = sidx & 3;
          const int sb = ts & 1, mat = tau & 1, skh = tau >> 1;
          const int kbase = ts * 64 + skh * 32;
          const short* g0 = (mat ? bG : aG) + kbase;
#pragma unroll
          for (int j = 0; j < 2; ++j) {
            const int r0 = (w * 2 + j) * 16;
            gload_lds16(g0 + (size_t)r0 * K, (char*)&SM[sb][mat][skh][r0][0]);
          }
          ++sidx;
        }
      }
      bf16x8 af[4], bf[4];
#pragma unroll
      for (int m = 0; m < 4; ++m)
        af[m] = *(const bf16x8*)&SM[buf][0][kh][wm * 64 + m * 16 + fr][slot8];
#pragma unroll
      for (int n = 0; n < 4; ++n)
        bf[n] = *(const bf16x8*)&SM[buf][1][kh][wn * 64 + n * 16 + fr][slot8];
      BAR();
      __builtin_amdgcn_s_setprio(1);
#pragma unroll
      for (int m = 0; m < 4; ++m)
#pragma unroll
        for (int n = 0; n < 4; ++n)
          acc[m][n] = __builtin_amdgcn_mfma_f32_16x16x32_bf16(
              af[m], bf[n], acc[m][n], 0, 0, 0);
      __builtin_amdgcn_s_setprio(0);
      if (!(t == NT - 1 && p == 1)) {
        if (t == NT - 1 && p == 0) { VMW(0); }
        else if (t == NT - 2 && p == 1) { VMW(4); }
        else { VMW(8); }
        BAR();
      }
    }
  }

#pragma unroll
  for (int n = 0; n < 4; ++n) {
    const int col = bcol + wn * 64 + n * 16 + fr;
    const float bv = bias[col];
#pragma unroll
    for (int i = 0; i < 4; ++i) {
      const size_t row = brow + (size_t)(wm * 64 + i * 16 + fg * 4);
#pragma unroll
      for (int r = 0; r < 4; ++r) {
        const float v = acc[i][n][r] + bv;
        if (F32OUT)
          ((float*)Cout)[(row + r) * (size_t)N + col] = v;
        else
          ((short*)Cout)[(row + r) * (size_t)N + col] = f2bf(v);
      }
    }
  }
}

// ---------------- fused anti-causal flash attention (keep k >= q) ----------------
// R19/R20-verified: KVBLK=64 (8 blocks/CU), no-max softmax, Q-prescale, hw cvt,
// V-reg prefetch, K staged post-sync2, denominator via P·ones MFMA.
__global__ __launch_bounds__(256) void k_attn(
    const short* __restrict__ qkv, short* __restrict__ outc, int Bn, int S) {
  __shared__ short Ks[64][64];    // 16B slots XOR-swizzled within 128B rows
  __shared__ short Vt[64][72];    // V^T, padded pitch

  const int tid = threadIdx.x;
  const int w = tid >> 6, l = tid & 63;
  const int fr = l & 15, fg = l >> 4;

  const int tq = blockIdx.x >> 7;        // 0..15, longest work first (LPT)
  const int bh = blockIdx.x & 127;
  const int h = bh & 15, b = bh >> 4;
  const int q0 = tq << 6;

  const size_t rowbase = (size_t)b * S;
  const int qcol = q0 + w * 16 + fr;

  bf16x8 qf[2];
  {
    const short* qp = qkv + (rowbase + qcol) * 3072 + h * 64 + fg * 8;
    qf[0] = *(const bf16x8*)qp;
    qf[1] = *(const bf16x8*)(qp + 32);
    const float C2 = 0.04508422f;
#pragma unroll
    for (int j = 0; j < 8; ++j) {
      union { float f; uint32_t u; } ca, cb;
      ca.u = ((uint32_t)(uint16_t)qf[0][j]) << 16;
      cb.u = ((uint32_t)(uint16_t)qf[1][j]) << 16;
      qf[0][j] = f2bf_hw(ca.f * C2);
      qf[1][j] = f2bf_hw(cb.f * C2);
    }
  }

  f32x4 o[4] = {};
  f32x4 ol = {};   // softmax denominator via MFMA (P · ones)
  const short ONE = (short)0x3F80;  // bf16 1.0
  const bf16x8 vones = {ONE, ONE, ONE, ONE, ONE, ONE, ONE, ONE};

  const short* Kbase = qkv + rowbase * 3072 + 1024 + h * 64;
  const short* Vbase = qkv + rowbase * 3072 + 2048 + h * 64;

  const int r8 = l >> 3, slot = l & 7;
  const int vdb = (tid >> 4) << 2;       // 0..60, V col (d) block
  const int vkb = (tid & 15) << 2;       // 0..60, V row (k) block

#define STAGE_K(c)                                                             \
  {                                                                            \
    const int k0s = (c) << 6;                                                  \
    _Pragma("unroll") for (int j = 0; j < 2; ++j) {                            \
      int ch = w * 2 + j;                                                      \
      int row = ch * 8 + r8;                                                   \
      int d = (slot ^ (row & 7)) << 3;                                         \
      gload_lds16(Kbase + (size_t)(k0s + row) * 3072 + d,                      \
                  (char*)&Ks[0][0] + ch * 1024);                               \
    }                                                                          \
  }
#define LOAD_V(c)                                                              \
  {                                                                            \
    const int k0s = (c) << 6;                                                  \
    const short* vp = Vbase + (size_t)(k0s + vkb) * 3072 + vdb;                \
    vr[0] = *(const short4v*)(vp);                                             \
    vr[1] = *(const short4v*)(vp + 3072);                                      \
    vr[2] = *(const short4v*)(vp + 2 * 3072);                                  \
    vr[3] = *(const short4v*)(vp + 3 * 3072);                                  \
  }

  const int c0 = tq;
  short4v vr[4];
  STAGE_K(c0);
  LOAD_V(c0);

  for (int c = c0; c < 16; ++c) {
    const int k0 = c << 6;
    VMW(0);          // K(c) in LDS, vr(c) complete (aged from prev step)
    __syncthreads(); // sync1: prev PV done -> Vt free; K(c) visible

    {
      short4v t0 = {vr[0].x, vr[1].x, vr[2].x, vr[3].x};
      short4v t1 = {vr[0].y, vr[1].y, vr[2].y, vr[3].y};
      short4v t2 = {vr[0].z, vr[1].z, vr[2].z, vr[3].z};
      short4v t3 = {vr[0].w, vr[1].w, vr[2].w, vr[3].w};
      *(short4v*)&Vt[vdb + 0][vkb] = t0;
      *(short4v*)&Vt[vdb + 1][vkb] = t1;
      *(short4v*)&Vt[vdb + 2][vkb] = t2;
      *(short4v*)&Vt[vdb + 3][vkb] = t3;
    }

    f32x4 st[4];
#pragma unroll
    for (int kb = 0; kb < 4; ++kb) {
      f32x4 z = {0.f, 0.f, 0.f, 0.f};
      int row = kb * 16 + fr;
      int sw = row & 7;
      bf16x8 kf0 = *(const bf16x8*)&Ks[row][(fg ^ sw) << 3];
      bf16x8 kf1 = *(const bf16x8*)&Ks[row][((4 + fg) ^ sw) << 3];
      z = __builtin_amdgcn_mfma_f32_16x16x32_bf16(kf0, qf[0], z, 0, 0, 0);
      z = __builtin_amdgcn_mfma_f32_16x16x32_bf16(kf1, qf[1], z, 0, 0, 0);
      st[kb] = z;
    }

    if (c + 1 < 16) LOAD_V(c + 1);

    const bool masked = (c == c0);
#pragma unroll
    for (int kb = 0; kb < 4; ++kb)
#pragma unroll
      for (int r = 0; r < 4; ++r) {
        float e = exp2f(st[kb][r]);
        if (masked) {
          int kg = k0 + kb * 16 + fg * 4 + r;
          e = (kg < qcol) ? 0.0f : e;
        }
        st[kb][r] = e;
      }

    __syncthreads(); // sync2: all QK(c) done -> Ks free; Vt(c) writes visible

    if (c + 1 < 16) STAGE_K(c + 1);

#pragma unroll
    for (int kb2 = 0; kb2 < 2; ++kb2) {
      bf16x8 pa = {f2bf_hw(st[2 * kb2][0]),     f2bf_hw(st[2 * kb2][1]),
                   f2bf_hw(st[2 * kb2][2]),     f2bf_hw(st[2 * kb2][3]),
                   f2bf_hw(st[2 * kb2 + 1][0]), f2bf_hw(st[2 * kb2 + 1][1]),
                   f2bf_hw(st[2 * kb2 + 1][2]), f2bf_hw(st[2 * kb2 + 1][3])};
      ol = __builtin_amdgcn_mfma_f32_16x16x32_bf16(pa, vones, ol, 0, 0, 0);
#pragma unroll
      for (int f = 0; f < 4; ++f) {
        short4v v0 = *(const short4v*)&Vt[f * 16 + fr][kb2 * 32 + fg * 4];
        short4v v1 = *(const short4v*)&Vt[f * 16 + fr][kb2 * 32 + 16 + fg * 4];
        bf16x8 vb = {v0.x, v0.y, v0.z, v0.w, v1.x, v1.y, v1.z, v1.w};
        o[f] = __builtin_amdgcn_mfma_f32_16x16x32_bf16(pa, vb, o[f], 0, 0, 0);
      }
    }
  }
#undef STAGE_K
#undef LOAD_V

#pragma unroll
  for (int r = 0; r < 4; ++r) {
    float inv = 1.0f / ol[r];
    size_t orow = rowbase + (size_t)(q0 + w * 16 + fg * 4 + r);
    short* op = outc + orow * 1024 + h * 64 + fr;
#pragma unroll
    for (int f = 0; f < 4; ++f) op[f * 16] = f2bf(o[f][r] * inv);
  }
}

extern "C" void kernel_launch(void* const* d_in, const int* in_sizes, int n_in,
                              void* d_out, int out_size, void* d_ws,
                              size_t ws_size, hipStream_t stream) {
  const float* x = (const float*)d_in[0];
  const float* Wc = (const float*)d_in[1];
  const float* bc = (const float*)d_in[2];
  const float* Wo = (const float*)d_in[3];
  const float* bo = (const float*)d_in[4];
  float* out = (float*)d_out;

  const int Bn = 8, S = 1024, D = 1024;
  const int M = Bn * S;  // 8192

  char* ws = (char*)d_ws;
  short* xb  = (short*)(ws);                               // 16 MB
  short* wct = (short*)(ws + (size_t)16 * 1024 * 1024);    // 6 MB  [3072][1024]
  short* wot = (short*)(ws + (size_t)22 * 1024 * 1024);    // 2 MB  [1024][1024]
  short* qkv = (short*)(ws + (size_t)24 * 1024 * 1024);    // 48 MB [8192][3072]
  short* cat = (short*)(ws + (size_t)72 * 1024 * 1024);    // 16 MB [8192][1024]

  k_prep<<<2048, 256, 0, stream>>>(x, xb, M * D / 4, Wc, wct, Wo, wot);
  k_g256<false><<<(M / 256) * (3 * D / 256), 512, 0, stream>>>(
      xb, wct, bc, qkv, M, 3 * D, D, 3 * D / 256);
  k_attn<<<16 * 128, 256, 0, stream>>>(qkv, cat, Bn, S);
  k_gemm2<true><<<(M / 128) * (D / 128), 256, 0, stream>>>(
      cat, wot, bo, out, M, D, D, D / 128);
}

// Round 22
// 151.579 us; speedup vs baseline: 1.0462x; 1.0462x over previous
//
#include <hip/hip_runtime.h>
#include <stdint.h>

typedef __attribute__((ext_vector_type(8))) short  bf16x8;
typedef __attribute__((ext_vector_type(4))) short  short4v;
typedef __attribute__((ext_vector_type(4))) float  f32x4;
typedef __attribute__((ext_vector_type(4))) float  float4v;

#define VMW(N) asm volatile("s_waitcnt vmcnt(" #N ")" ::: "memory")
#define BAR()  asm volatile("s_barrier" ::: "memory")

__device__ __forceinline__ short f2bf(float f) {
  union { float f; uint32_t u; } c; c.f = f;
  uint32_t u = c.u;
  uint32_t r = (u + 0x7FFFu + ((u >> 16) & 1u)) >> 16;
  return (short)(uint16_t)r;
}

// hardware bf16 convert (compiler emits v_cvt_pk_bf16_f32 for pairs)
__device__ __forceinline__ short f2bf_hw(float f) {
  return __builtin_bit_cast(short, (__bf16)f);
}

__device__ __forceinline__ void gload_lds16(const void* g, void* l) {
  __builtin_amdgcn_global_load_lds(
      (const __attribute__((address_space(1))) void*)g,
      (__attribute__((address_space(3))) void*)l, 16, 0, 0);
}

// ---------- fused prep: x cast (blocks 0..1023), Wc^T (1024..1791), Wo^T ----------
__device__ __forceinline__ void transpose_body(
    const float* __restrict__ in, short* __restrict__ out, int R, int C,
    int bx, int by, short (*tile)[65]) {
  int bc = bx * 64, br = by * 64;
  int tc = threadIdx.x & 63, tr = threadIdx.x >> 6;  // tr 0..3
#pragma unroll
  for (int i = 0; i < 64; i += 4)
    tile[tc][tr + i] = f2bf(in[(size_t)(br + tr + i) * C + bc + tc]);
  __syncthreads();
#pragma unroll
  for (int i = 0; i < 64; i += 4)
    out[(size_t)(bc + tr + i) * R + br + tc] = tile[tr + i][tc];
}

__global__ __launch_bounds__(256) void k_prep(
    const float* __restrict__ x, short* __restrict__ xb, int n4,
    const float* __restrict__ Wc, short* __restrict__ wct,
    const float* __restrict__ Wo, short* __restrict__ wot) {
  __shared__ short tile[64][65];
  const int id = blockIdx.x;
  if (id < 1024) {  // cast: grid-stride, 1024 blocks
    const int stride = 1024 * 256;
    for (int i = id * 256 + threadIdx.x; i < n4; i += stride) {
      float4v v = *(const float4v*)(x + (size_t)i * 4);
      short4v o;
      o.x = f2bf(v.x); o.y = f2bf(v.y); o.z = f2bf(v.z); o.w = f2bf(v.w);
      *(short4v*)(xb + (size_t)i * 4) = o;
    }
  } else if (id < 1024 + 768) {  // Wc [1024][3072] -> wct [3072][1024]
    int t = id - 1024;
    transpose_body(Wc, wct, 1024, 3072, t % 48, t / 48, tile);
  } else {  // Wo [1024][1024] -> wot [1024][1024]
    int t = id - 1792;
    transpose_body(Wo, wot, 1024, 1024, t & 15, t >> 4, tile);
  }
}

// ------------- GEMM (R6/R15-verified best): 128x128, BK=64, two-phase counted ------
template <bool F32OUT>
__global__ __launch_bounds__(256) void k_gemm2(
    const short* __restrict__ A, const short* __restrict__ BT,
    const float* __restrict__ bias, void* __restrict__ Cout,
    int M, int N, int K, int nbn) {
  __shared__ short SM[2][2][2][128][32];  // [buf][mat(A=0,B=1)][kh][row][kcol]
  const int tid = threadIdx.x;
  const int w = tid >> 6, l = tid & 63;
  const int fr = l & 15, fg = l >> 4;
  const int wm = w >> 1, wn = w & 1;

  const int q8 = gridDim.x >> 3;
  const int wg = (blockIdx.x & 7) * q8 + (blockIdx.x >> 3);
  const int bm = wg / nbn, bn = wg % nbn;
  const size_t brow = (size_t)bm << 7;
  const int bcol = bn << 7;

  const int NT = K >> 6;

  const int srow = l >> 2;
  const int soct = (l & 3) ^ ((l >> 3) & 3);
  const short* aG = A + (brow + srow) * (size_t)K + soct * 8;
  const short* bG = BT + ((size_t)(bcol + srow)) * K + soct * 8;
  const int slot8 = ((fg ^ ((fr >> 1) & 3)) << 3);

  f32x4 acc[4][4] = {};

#pragma unroll
  for (int s = 0; s < 6; ++s) {
    const int t = s >> 2, tau = s & 3, buf = t & 1, mat = tau & 1, kh = tau >> 1;
    const int kbase = t * 64 + kh * 32;
    const short* g0 = (mat ? bG : aG) + kbase;
#pragma unroll
    for (int j = 0; j < 2; ++j) {
      const int r0 = (w * 2 + j) * 16;
      gload_lds16(g0 + (size_t)r0 * K, (char*)&SM[buf][mat][kh][r0][0]);
    }
  }
  VMW(8);
  BAR();

  int sidx = 6;
  for (int t = 0; t < NT; ++t) {
    const int buf = t & 1;
#pragma unroll
    for (int p = 0; p < 2; ++p) {
      const int kh = p;
#pragma unroll
      for (int s = 0; s < 2; ++s) {
        if (sidx < NT * 4) {
          const int ts = sidx >> 2, tau = sidx & 3;
          const int sb = ts & 1, mat = tau & 1, skh = tau >> 1;
          const int kbase = ts * 64 + skh * 32;
          const short* g0 = (mat ? bG : aG) + kbase;
#pragma unroll
          for (int j = 0; j < 2; ++j) {
            const int r0 = (w * 2 + j) * 16;
            gload_lds16(g0 + (size_t)r0 * K, (char*)&SM[sb][mat][skh][r0][0]);
          }
          ++sidx;
        }
      }
      bf16x8 af[4], bf[4];
#pragma unroll
      for (int m = 0; m < 4; ++m)
        af[m] = *(const bf16x8*)&SM[buf][0][kh][wm * 64 + m * 16 + fr][slot8];
#pragma unroll
      for (int n = 0; n < 4; ++n)
        bf[n] = *(const bf16x8*)&SM[buf][1][kh][wn * 64 + n * 16 + fr][slot8];
      BAR();
      __builtin_amdgcn_s_setprio(1);
#pragma unroll
      for (int m = 0; m < 4; ++m)
#pragma unroll
        for (int n = 0; n < 4; ++n)
          acc[m][n] = __builtin_amdgcn_mfma_f32_16x16x32_bf16(
              af[m], bf[n], acc[m][n], 0, 0, 0);
      __builtin_amdgcn_s_setprio(0);
      if (!(t == NT - 1 && p == 1)) {
        if (t == NT - 1 && p == 0) { VMW(0); }
        else if (t == NT - 2 && p == 1) { VMW(4); }
        else { VMW(8); }
        BAR();
      }
    }
  }

#pragma unroll
  for (int n = 0; n < 4; ++n) {
    const int col = bcol + wn * 64 + n * 16 + fr;
    const float bv = bias[col];
#pragma unroll
    for (int i = 0; i < 4; ++i) {
      const size_t row = brow + (size_t)(wm * 64 + i * 16 + fg * 4);
#pragma unroll
      for (int r = 0; r < 4; ++r) {
        const float v = acc[i][n][r] + bv;
        if (F32OUT)
          ((float*)Cout)[(row + r) * (size_t)N + col] = v;
        else
          ((short*)Cout)[(row + r) * (size_t)N + col] = f2bf(v);
      }
    }
  }
}

// ---------------- fused anti-causal flash attention (keep k >= q) ----------------
// R19/R20-verified: KVBLK=64 (8 blocks/CU), no-max softmax, Q-prescale, hw cvt,
// V-reg prefetch, K staged post-sync2, denominator via P·ones MFMA.
__global__ __launch_bounds__(256) void k_attn(
    const short* __restrict__ qkv, short* __restrict__ outc, int Bn, int S) {
  __shared__ short Ks[64][64];    // 16B slots XOR-swizzled within 128B rows
  __shared__ short Vt[64][72];    // V^T, padded pitch

  const int tid = threadIdx.x;
  const int w = tid >> 6, l = tid & 63;
  const int fr = l & 15, fg = l >> 4;

  const int tq = blockIdx.x >> 7;        // 0..15, longest work first (LPT)
  const int bh = blockIdx.x & 127;
  const int h = bh & 15, b = bh >> 4;
  const int q0 = tq << 6;

  const size_t rowbase = (size_t)b * S;
  const int qcol = q0 + w * 16 + fr;

  bf16x8 qf[2];
  {
    const short* qp = qkv + (rowbase + qcol) * 3072 + h * 64 + fg * 8;
    qf[0] = *(const bf16x8*)qp;
    qf[1] = *(const bf16x8*)(qp + 32);
    const float C2 = 0.04508422f;
#pragma unroll
    for (int j = 0; j < 8; ++j) {
      union { float f; uint32_t u; } ca, cb;
      ca.u = ((uint32_t)(uint16_t)qf[0][j]) << 16;
      cb.u = ((uint32_t)(uint16_t)qf[1][j]) << 16;
      qf[0][j] = f2bf_hw(ca.f * C2);
      qf[1][j] = f2bf_hw(cb.f * C2);
    }
  }

  f32x4 o[4] = {};
  f32x4 ol = {};   // softmax denominator via MFMA (P · ones)
  const short ONE = (short)0x3F80;  // bf16 1.0
  const bf16x8 vones = {ONE, ONE, ONE, ONE, ONE, ONE, ONE, ONE};

  const short* Kbase = qkv + rowbase * 3072 + 1024 + h * 64;
  const short* Vbase = qkv + rowbase * 3072 + 2048 + h * 64;

  const int r8 = l >> 3, slot = l & 7;
  const int vdb = (tid >> 4) << 2;       // 0..60, V col (d) block
  const int vkb = (tid & 15) << 2;       // 0..60, V row (k) block

#define STAGE_K(c)                                                             \
  {                                                                            \
    const int k0s = (c) << 6;                                                  \
    _Pragma("unroll") for (int j = 0; j < 2; ++j) {                            \
      int ch = w * 2 + j;                                                      \
      int row = ch * 8 + r8;                                                   \
      int d = (slot ^ (row & 7)) << 3;                                         \
      gload_lds16(Kbase + (size_t)(k0s + row) * 3072 + d,                      \
                  (char*)&Ks[0][0] + ch * 1024);                               \
    }                                                                          \
  }
#define LOAD_V(c)                                                              \
  {                                                                            \
    const int k0s = (c) << 6;                                                  \
    const short* vp = Vbase + (size_t)(k0s + vkb) * 3072 + vdb;                \
    vr[0] = *(const short4v*)(vp);                                             \
    vr[1] = *(const short4v*)(vp + 3072);                                      \
    vr[2] = *(const short4v*)(vp + 2 * 3072);                                  \
    vr[3] = *(const short4v*)(vp + 3 * 3072);                                  \
  }

  const int c0 = tq;
  short4v vr[4];
  STAGE_K(c0);
  LOAD_V(c0);

  for (int c = c0; c < 16; ++c) {
    const int k0 = c << 6;
    VMW(0);          // K(c) in LDS, vr(c) complete (aged from prev step)
    __syncthreads(); // sync1: prev PV done -> Vt free; K(c) visible

    {
      short4v t0 = {vr[0].x, vr[1].x, vr[2].x, vr[3].x};
      short4v t1 = {vr[0].y, vr[1].y, vr[2].y, vr[3].y};
      short4v t2 = {vr[0].z, vr[1].z, vr[2].z, vr[3].z};
      short4v t3 = {vr[0].w, vr[1].w, vr[2].w, vr[3].w};
      *(short4v*)&Vt[vdb + 0][vkb] = t0;
      *(short4v*)&Vt[vdb + 1][vkb] = t1;
      *(short4v*)&Vt[vdb + 2][vkb] = t2;
      *(short4v*)&Vt[vdb + 3][vkb] = t3;
    }

    f32x4 st[4];
#pragma unroll
    for (int kb = 0; kb < 4; ++kb) {
      f32x4 z = {0.f, 0.f, 0.f, 0.f};
      int row = kb * 16 + fr;
      int sw = row & 7;
      bf16x8 kf0 = *(const bf16x8*)&Ks[row][(fg ^ sw) << 3];
      bf16x8 kf1 = *(const bf16x8*)&Ks[row][((4 + fg) ^ sw) << 3];
      z = __builtin_amdgcn_mfma_f32_16x16x32_bf16(kf0, qf[0], z, 0, 0, 0);
      z = __builtin_amdgcn_mfma_f32_16x16x32_bf16(kf1, qf[1], z, 0, 0, 0);
      st[kb] = z;
    }

    if (c + 1 < 16) LOAD_V(c + 1);

    const bool masked = (c == c0);
#pragma unroll
    for (int kb = 0; kb < 4; ++kb)
#pragma unroll
      for (int r = 0; r < 4; ++r) {
        float e = exp2f(st[kb][r]);
        if (masked) {
          int kg = k0 + kb * 16 + fg * 4 + r;
          e = (kg < qcol) ? 0.0f : e;
        }
        st[kb][r] = e;
      }

    __syncthreads(); // sync2: all QK(c) done -> Ks free; Vt(c) writes visible

    if (c + 1 < 16) STAGE_K(c + 1);

#pragma unroll
    for (int kb2 = 0; kb2 < 2; ++kb2) {
      bf16x8 pa = {f2bf_hw(st[2 * kb2][0]),     f2bf_hw(st[2 * kb2][1]),
                   f2bf_hw(st[2 * kb2][2]),     f2bf_hw(st[2 * kb2][3]),
                   f2bf_hw(st[2 * kb2 + 1][0]), f2bf_hw(st[2 * kb2 + 1][1]),
                   f2bf_hw(st[2 * kb2 + 1][2]), f2bf_hw(st[2 * kb2 + 1][3])};
      ol = __builtin_amdgcn_mfma_f32_16x16x32_bf16(pa, vones, ol, 0, 0, 0);
#pragma unroll
      for (int f = 0; f < 4; ++f) {
        short4v v0 = *(const short4v*)&Vt[f * 16 + fr][kb2 * 32 + fg * 4];
        short4v v1 = *(const short4v*)&Vt[f * 16 + fr][kb2 * 32 + 16 + fg * 4];
        bf16x8 vb = {v0.x, v0.y, v0.z, v0.w, v1.x, v1.y, v1.z, v1.w};
        o[f] = __builtin_amdgcn_mfma_f32_16x16x32_bf16(pa, vb, o[f], 0, 0, 0);
      }
    }
  }
#undef STAGE_K
#undef LOAD_V

#pragma unroll
  for (int r = 0; r < 4; ++r) {
    float inv = 1.0f / ol[r];
    size_t orow = rowbase + (size_t)(q0 + w * 16 + fg * 4 + r);
    short* op = outc + orow * 1024 + h * 64 + fr;
#pragma unroll
    for (int f = 0; f < 4; ++f) op[f * 16] = f2bf(o[f][r] * inv);
  }
}

extern "C" void kernel_launch(void* const* d_in, const int* in_sizes, int n_in,
                              void* d_out, int out_size, void* d_ws,
                              size_t ws_size, hipStream_t stream) {
  const float* x = (const float*)d_in[0];
  const float* Wc = (const float*)d_in[1];
  const float* bc = (const float*)d_in[2];
  const float* Wo = (const float*)d_in[3];
  const float* bo = (const float*)d_in[4];
  float* out = (float*)d_out;

  const int Bn = 8, S = 1024, D = 1024;
  const int M = Bn * S;  // 8192

  char* ws = (char*)d_ws;
  short* xb  = (short*)(ws);                               // 16 MB
  short* wct = (short*)(ws + (size_t)16 * 1024 * 1024);    // 6 MB  [3072][1024]
  short* wot = (short*)(ws + (size_t)22 * 1024 * 1024);    // 2 MB  [1024][1024]
  short* qkv = (short*)(ws + (size_t)24 * 1024 * 1024);    // 48 MB [8192][3072]
  short* cat = (short*)(ws + (size_t)72 * 1024 * 1024);    // 16 MB [8192][1024]

  k_prep<<<2048, 256, 0, stream>>>(x, xb, M * D / 4, Wc, wct, Wo, wot);
  k_gemm2<false><<<(M / 128) * (3 * D / 128), 256, 0, stream>>>(
      xb, wct, bc, qkv, M, 3 * D, D, 3 * D / 128);
  k_attn<<<16 * 128, 256, 0, stream>>>(qkv, cat, Bn, S);
  k_gemm2<true><<<(M / 128) * (D / 128), 256, 0, stream>>>(
      cat, wot, bo, out, M, D, D, D / 128);
}

// Round 23
// 151.015 us; speedup vs baseline: 1.0501x; 1.0037x over previous
//
#include <hip/hip_runtime.h>
#include <stdint.h>

typedef __attribute__((ext_vector_type(8))) short  bf16x8;
typedef __attribute__((ext_vector_type(4))) short  short4v;
typedef __attribute__((ext_vector_type(4))) float  f32x4;
typedef __attribute__((ext_vector_type(4))) float  float4v;

#define VMW(N) asm volatile("s_waitcnt vmcnt(" #N ")" ::: "memory")
#define BAR()  asm volatile("s_barrier" ::: "memory")

__device__ __forceinline__ short f2bf(float f) {
  union { float f; uint32_t u; } c; c.f = f;
  uint32_t u = c.u;
  uint32_t r = (u + 0x7FFFu + ((u >> 16) & 1u)) >> 16;
  return (short)(uint16_t)r;
}

// hardware bf16 convert (compiler emits v_cvt_pk_bf16_f32 for pairs)
__device__ __forceinline__ short f2bf_hw(float f) {
  return __builtin_bit_cast(short, (__bf16)f);
}

__device__ __forceinline__ void gload_lds16(const void* g, void* l) {
  __builtin_amdgcn_global_load_lds(
      (const __attribute__((address_space(1))) void*)g,
      (__attribute__((address_space(3))) void*)l, 16, 0, 0);
}

// ---------- fused prep: x cast (blocks 0..1023), Wc^T (1024..1791), Wo^T ----------
__device__ __forceinline__ void transpose_body(
    const float* __restrict__ in, short* __restrict__ out, int R, int C,
    int bx, int by, short (*tile)[65]) {
  int bc = bx * 64, br = by * 64;
  int tc = threadIdx.x & 63, tr = threadIdx.x >> 6;  // tr 0..3
#pragma unroll
  for (int i = 0; i < 64; i += 4)
    tile[tc][tr + i] = f2bf(in[(size_t)(br + tr + i) * C + bc + tc]);
  __syncthreads();
#pragma unroll
  for (int i = 0; i < 64; i += 4)
    out[(size_t)(bc + tr + i) * R + br + tc] = tile[tr + i][tc];
}

__global__ __launch_bounds__(256) void k_prep(
    const float* __restrict__ x, short* __restrict__ xb, int n4,
    const float* __restrict__ Wc, short* __restrict__ wct,
    const float* __restrict__ Wo, short* __restrict__ wot) {
  __shared__ short tile[64][65];
  const int id = blockIdx.x;
  if (id < 1024) {  // cast: grid-stride, 1024 blocks
    const int stride = 1024 * 256;
    for (int i = id * 256 + threadIdx.x; i < n4; i += stride) {
      float4v v = *(const float4v*)(x + (size_t)i * 4);
      short4v o;
      o.x = f2bf(v.x); o.y = f2bf(v.y); o.z = f2bf(v.z); o.w = f2bf(v.w);
      *(short4v*)(xb + (size_t)i * 4) = o;
    }
  } else if (id < 1024 + 768) {  // Wc [1024][3072] -> wct [3072][1024]
    int t = id - 1024;
    transpose_body(Wc, wct, 1024, 3072, t % 48, t / 48, tile);
  } else {  // Wo [1024][1024] -> wot [1024][1024]
    int t = id - 1792;
    transpose_body(Wo, wot, 1024, 1024, t & 15, t >> 4, tile);
  }
}

// ------------- GEMM (R6/R15-verified best): 128x128, BK=64, two-phase counted ------
template <bool F32OUT>
__global__ __launch_bounds__(256) void k_gemm2(
    const short* __restrict__ A, const short* __restrict__ BT,
    const float* __restrict__ bias, void* __restrict__ Cout,
    int M, int N, int K, int nbn) {
  __shared__ short SM[2][2][2][128][32];  // [buf][mat(A=0,B=1)][kh][row][kcol]
  const int tid = threadIdx.x;
  const int w = tid >> 6, l = tid & 63;
  const int fr = l & 15, fg = l >> 4;
  const int wm = w >> 1, wn = w & 1;

  const int q8 = gridDim.x >> 3;
  const int wg = (blockIdx.x & 7) * q8 + (blockIdx.x >> 3);
  const int bm = wg / nbn, bn = wg % nbn;
  const size_t brow = (size_t)bm << 7;
  const int bcol = bn << 7;

  const int NT = K >> 6;

  const int srow = l >> 2;
  const int soct = (l & 3) ^ ((l >> 3) & 3);
  const short* aG = A + (brow + srow) * (size_t)K + soct * 8;
  const short* bG = BT + ((size_t)(bcol + srow)) * K + soct * 8;
  const int slot8 = ((fg ^ ((fr >> 1) & 3)) << 3);

  f32x4 acc[4][4] = {};

#pragma unroll
  for (int s = 0; s < 6; ++s) {
    const int t = s >> 2, tau = s & 3, buf = t & 1, mat = tau & 1, kh = tau >> 1;
    const int kbase = t * 64 + kh * 32;
    const short* g0 = (mat ? bG : aG) + kbase;
#pragma unroll
    for (int j = 0; j < 2; ++j) {
      const int r0 = (w * 2 + j) * 16;
      gload_lds16(g0 + (size_t)r0 * K, (char*)&SM[buf][mat][kh][r0][0]);
    }
  }
  VMW(8);
  BAR();

  int sidx = 6;
  for (int t = 0; t < NT; ++t) {
    const int buf = t & 1;
#pragma unroll
    for (int p = 0; p < 2; ++p) {
      const int kh = p;
#pragma unroll
      for (int s = 0; s < 2; ++s) {
        if (sidx < NT * 4) {
          const int ts = sidx >> 2, tau = sidx & 3;
          const int sb = ts & 1, mat = tau & 1, skh = tau >> 1;
          const int kbase = ts * 64 + skh * 32;
          const short* g0 = (mat ? bG : aG) + kbase;
#pragma unroll
          for (int j = 0; j < 2; ++j) {
            const int r0 = (w * 2 + j) * 16;
            gload_lds16(g0 + (size_t)r0 * K, (char*)&SM[sb][mat][skh][r0][0]);
          }
          ++sidx;
        }
      }
      bf16x8 af[4], bf[4];
#pragma unroll
      for (int m = 0; m < 4; ++m)
        af[m] = *(const bf16x8*)&SM[buf][0][kh][wm * 64 + m * 16 + fr][slot8];
#pragma unroll
      for (int n = 0; n < 4; ++n)
        bf[n] = *(const bf16x8*)&SM[buf][1][kh][wn * 64 + n * 16 + fr][slot8];
      BAR();
      __builtin_amdgcn_s_setprio(1);
#pragma unroll
      for (int m = 0; m < 4; ++m)
#pragma unroll
        for (int n = 0; n < 4; ++n)
          acc[m][n] = __builtin_amdgcn_mfma_f32_16x16x32_bf16(
              af[m], bf[n], acc[m][n], 0, 0, 0);
      __builtin_amdgcn_s_setprio(0);
      if (!(t == NT - 1 && p == 1)) {
        if (t == NT - 1 && p == 0) { VMW(0); }
        else if (t == NT - 2 && p == 1) { VMW(4); }
        else { VMW(8); }
        BAR();
      }
    }
  }

#pragma unroll
  for (int n = 0; n < 4; ++n) {
    const int col = bcol + wn * 64 + n * 16 + fr;
    const float bv = bias[col];
#pragma unroll
    for (int i = 0; i < 4; ++i) {
      const size_t row = brow + (size_t)(wm * 64 + i * 16 + fg * 4);
#pragma unroll
      for (int r = 0; r < 4; ++r) {
        const float v = acc[i][n][r] + bv;
        if (F32OUT)
          ((float*)Cout)[(row + r) * (size_t)N + col] = v;
        else
          ((short*)Cout)[(row + r) * (size_t)N + col] = f2bf(v);
      }
    }
  }
}

// ---------------- fused anti-causal flash attention (keep k >= q) ----------------
// R19/R20-verified: KVBLK=64 (8 blocks/CU), no-max softmax, Q-prescale, hw cvt,
// V-reg prefetch, K staged post-sync2, denominator via P·ones MFMA.
__global__ __launch_bounds__(256) void k_attn(
    const short* __restrict__ qkv, short* __restrict__ outc, int Bn, int S) {
  __shared__ short Ks[64][64];    // 16B slots XOR-swizzled within 128B rows
  __shared__ short Vt[64][72];    // V^T, padded pitch

  const int tid = threadIdx.x;
  const int w = tid >> 6, l = tid & 63;
  const int fr = l & 15, fg = l >> 4;

  const int tq = blockIdx.x >> 7;        // 0..15, longest work first (LPT)
  const int bh = blockIdx.x & 127;
  const int h = bh & 15, b = bh >> 4;
  const int q0 = tq << 6;

  const size_t rowbase = (size_t)b * S;
  const int qcol = q0 + w * 16 + fr;

  bf16x8 qf[2];
  {
    const short* qp = qkv + (rowbase + qcol) * 3072 + h * 64 + fg * 8;
    qf[0] = *(const bf16x8*)qp;
    qf[1] = *(const bf16x8*)(qp + 32);
    const float C2 = 0.04508422f;
#pragma unroll
    for (int j = 0; j < 8; ++j) {
      union { float f; uint32_t u; } ca, cb;
      ca.u = ((uint32_t)(uint16_t)qf[0][j]) << 16;
      cb.u = ((uint32_t)(uint16_t)qf[1][j]) << 16;
      qf[0][j] = f2bf_hw(ca.f * C2);
      qf[1][j] = f2bf_hw(cb.f * C2);
    }
  }

  f32x4 o[4] = {};
  f32x4 ol = {};   // softmax denominator via MFMA (P · ones)
  const short ONE = (short)0x3F80;  // bf16 1.0
  const bf16x8 vones = {ONE, ONE, ONE, ONE, ONE, ONE, ONE, ONE};

  const short* Kbase = qkv + rowbase * 3072 + 1024 + h * 64;
  const short* Vbase = qkv + rowbase * 3072 + 2048 + h * 64;

  const int r8 = l >> 3, slot = l & 7;
  const int vdb = (tid >> 4) << 2;       // 0..60, V col (d) block
  const int vkb = (tid & 15) << 2;       // 0..60, V row (k) block

#define STAGE_K(c)                                                             \
  {                                                                            \
    const int k0s = (c) << 6;                                                  \
    _Pragma("unroll") for (int j = 0; j < 2; ++j) {                            \
      int ch = w * 2 + j;                                                      \
      int row = ch * 8 + r8;                                                   \
      int d = (slot ^ (row & 7)) << 3;                                         \
      gload_lds16(Kbase + (size_t)(k0s + row) * 3072 + d,                      \
                  (char*)&Ks[0][0] + ch * 1024);                               \
    }                                                                          \
  }
#define LOAD_V(c)                                                              \
  {                                                                            \
    const int k0s = (c) << 6;                                                  \
    const short* vp = Vbase + (size_t)(k0s + vkb) * 3072 + vdb;                \
    vr[0] = *(const short4v*)(vp);                                             \
    vr[1] = *(const short4v*)(vp + 3072);                                      \
    vr[2] = *(const short4v*)(vp + 2 * 3072);                                  \
    vr[3] = *(const short4v*)(vp + 3 * 3072);                                  \
  }

  const int c0 = tq;
  short4v vr[4];
  STAGE_K(c0);
  LOAD_V(c0);

  for (int c = c0; c < 16; ++c) {
    const int k0 = c << 6;
    VMW(0);          // K(c) in LDS, vr(c) complete (aged from prev step)
    __syncthreads(); // sync1: prev PV done -> Vt free; K(c) visible

    {
      short4v t0 = {vr[0].x, vr[1].x, vr[2].x, vr[3].x};
      short4v t1 = {vr[0].y, vr[1].y, vr[2].y, vr[3].y};
      short4v t2 = {vr[0].z, vr[1].z, vr[2].z, vr[3].z};
      short4v t3 = {vr[0].w, vr[1].w, vr[2].w, vr[3].w};
      *(short4v*)&Vt[vdb + 0][vkb] = t0;
      *(short4v*)&Vt[vdb + 1][vkb] = t1;
      *(short4v*)&Vt[vdb + 2][vkb] = t2;
      *(short4v*)&Vt[vdb + 3][vkb] = t3;
    }

    f32x4 st[4];
#pragma unroll
    for (int kb = 0; kb < 4; ++kb) {
      f32x4 z = {0.f, 0.f, 0.f, 0.f};
      int row = kb * 16 + fr;
      int sw = row & 7;
      bf16x8 kf0 = *(const bf16x8*)&Ks[row][(fg ^ sw) << 3];
      bf16x8 kf1 = *(const bf16x8*)&Ks[row][((4 + fg) ^ sw) << 3];
      z = __builtin_amdgcn_mfma_f32_16x16x32_bf16(kf0, qf[0], z, 0, 0, 0);
      z = __builtin_amdgcn_mfma_f32_16x16x32_bf16(kf1, qf[1], z, 0, 0, 0);
      st[kb] = z;
    }

    if (c + 1 < 16) LOAD_V(c + 1);

    const bool masked = (c == c0);
#pragma unroll
    for (int kb = 0; kb < 4; ++kb)
#pragma unroll
      for (int r = 0; r < 4; ++r) {
        float e = exp2f(st[kb][r]);
        if (masked) {
          int kg = k0 + kb * 16 + fg * 4 + r;
          e = (kg < qcol) ? 0.0f : e;
        }
        st[kb][r] = e;
      }

    __syncthreads(); // sync2: all QK(c) done -> Ks free; Vt(c) writes visible

    if (c + 1 < 16) STAGE_K(c + 1);

#pragma unroll
    for (int kb2 = 0; kb2 < 2; ++kb2) {
      bf16x8 pa = {f2bf_hw(st[2 * kb2][0]),     f2bf_hw(st[2 * kb2][1]),
                   f2bf_hw(st[2 * kb2][2]),     f2bf_hw(st[2 * kb2][3]),
                   f2bf_hw(st[2 * kb2 + 1][0]), f2bf_hw(st[2 * kb2 + 1][1]),
                   f2bf_hw(st[2 * kb2 + 1][2]), f2bf_hw(st[2 * kb2 + 1][3])};
      ol = __builtin_amdgcn_mfma_f32_16x16x32_bf16(pa, vones, ol, 0, 0, 0);
#pragma unroll
      for (int f = 0; f < 4; ++f) {
        short4v v0 = *(const short4v*)&Vt[f * 16 + fr][kb2 * 32 + fg * 4];
        short4v v1 = *(const short4v*)&Vt[f * 16 + fr][kb2 * 32 + 16 + fg * 4];
        bf16x8 vb = {v0.x, v0.y, v0.z, v0.w, v1.x, v1.y, v1.z, v1.w};
        o[f] = __builtin_amdgcn_mfma_f32_16x16x32_bf16(pa, vb, o[f], 0, 0, 0);
      }
    }
  }
#undef STAGE_K
#undef LOAD_V

#pragma unroll
  for (int r = 0; r < 4; ++r) {
    float inv = 1.0f / ol[r];
    size_t orow = rowbase + (size_t)(q0 + w * 16 + fg * 4 + r);
    short* op = outc + orow * 1024 + h * 64 + fr;
#pragma unroll
    for (int f = 0; f < 4; ++f) op[f * 16] = f2bf(o[f][r] * inv);
  }
}

extern "C" void kernel_launch(void* const* d_in, const int* in_sizes, int n_in,
                              void* d_out, int out_size, void* d_ws,
                              size_t ws_size, hipStream_t stream) {
  const float* x = (const float*)d_in[0];
  const float* Wc = (const float*)d_in[1];
  const float* bc = (const float*)d_in[2];
  const float* Wo = (const float*)d_in[3];
  const float* bo = (const float*)d_in[4];
  float* out = (float*)d_out;

  const int Bn = 8, S = 1024, D = 1024;
  const int M = Bn * S;  // 8192

  char* ws = (char*)d_ws;
  short* xb  = (short*)(ws);                               // 16 MB
  short* wct = (short*)(ws + (size_t)16 * 1024 * 1024);    // 6 MB  [3072][1024]
  short* wot = (short*)(ws + (size_t)22 * 1024 * 1024);    // 2 MB  [1024][1024]
  short* qkv = (short*)(ws + (size_t)24 * 1024 * 1024);    // 48 MB [8192][3072]
  short* cat = (short*)(ws + (size_t)72 * 1024 * 1024);    // 16 MB [8192][1024]

  k_prep<<<2048, 256, 0, stream>>>(x, xb, M * D / 4, Wc, wct, Wo, wot);
  k_gemm2<false><<<(M / 128) * (3 * D / 128), 256, 0, stream>>>(
      xb, wct, bc, qkv, M, 3 * D, D, 3 * D / 128);
  k_attn<<<16 * 128, 256, 0, stream>>>(qkv, cat, Bn, S);
  k_gemm2<true><<<(M / 128) * (D / 128), 256, 0, stream>>>(
      cat, wot, bo, out, M, D, D, D / 128);
}